// Round 1
// baseline (61.243 us; speedup 1.0000x reference)
//
#include <hip/hip_runtime.h>

// Problem constants (from reference):
//   x: (N=128, S=16, D=512) f32, FM: (S+1, H=4) f32, Agg: (1, S, H) f32,
//   source_index: (2^S-1, S) i32  [UNUSED -- algebraically eliminated]
// Identity: out[n,h,d] = sum_j (FM[j+1,h]*Agg[j,h]) * x[n,j,d]
// (sort + gap encoding + cumsum-code table lookup telescopes to a plain
//  weighted sum over the source axis, permutation-invariant).

#define CIE_S 16
#define CIE_H 4
#define CIE_N 128
#define CIE_D 512
#define CIE_D4 (CIE_D / 4)

__global__ __launch_bounds__(64)
void CIE_18236431138961_kernel(const float* __restrict__ x,
                               const float* __restrict__ FM,
                               const float* __restrict__ Agg,
                               float* __restrict__ out) {
    const int t  = blockIdx.x * 64 + threadIdx.x;   // 0 .. N*D4-1
    const int n  = t / CIE_D4;
    const int d4 = t % CIE_D4;

    // W[j][h] = FM[j+1][h] * Agg[j][h] -- uniform addresses, compiler emits
    // scalar loads; 64 regs total.
    float W[CIE_S][CIE_H];
#pragma unroll
    for (int j = 0; j < CIE_S; ++j) {
#pragma unroll
        for (int h = 0; h < CIE_H; ++h) {
            W[j][h] = FM[(j + 1) * CIE_H + h] * Agg[j * CIE_H + h];
        }
    }

    const float4* __restrict__ x4   = (const float4*)x;
    float4* __restrict__       out4 = (float4*)out;

    float4 acc[CIE_H];
#pragma unroll
    for (int h = 0; h < CIE_H; ++h) acc[h] = make_float4(0.f, 0.f, 0.f, 0.f);

#pragma unroll
    for (int j = 0; j < CIE_S; ++j) {
        const float4 v = x4[(n * CIE_S + j) * CIE_D4 + d4];
#pragma unroll
        for (int h = 0; h < CIE_H; ++h) {
            acc[h].x += W[j][h] * v.x;
            acc[h].y += W[j][h] * v.y;
            acc[h].z += W[j][h] * v.z;
            acc[h].w += W[j][h] * v.w;
        }
    }

#pragma unroll
    for (int h = 0; h < CIE_H; ++h) {
        out4[(n * CIE_H + h) * CIE_D4 + d4] = acc[h];
    }
}

extern "C" void kernel_launch(void* const* d_in, const int* in_sizes, int n_in,
                              void* d_out, int out_size, void* d_ws, size_t ws_size,
                              hipStream_t stream) {
    const float* x   = (const float*)d_in[0];
    const float* FM  = (const float*)d_in[1];
    const float* Agg = (const float*)d_in[2];
    // d_in[3] = source_index: unused (algebraically eliminated).
    float* out = (float*)d_out;

    const int total  = CIE_N * CIE_D4;   // 16384 threads
    const int block  = 64;
    const int grid   = total / block;    // 256 blocks -> ~1 per CU

    CIE_18236431138961_kernel<<<grid, block, 0, stream>>>(x, FM, Agg, out);
}